// Round 1
// baseline (195.737 us; speedup 1.0000x reference)
//
#include <hip/hip_runtime.h>
#include <hip/hip_bf16.h>

// Averaged Hausdorff distance between two 16384x3 fp32 point sets.
// term1 = mean_i min_j ||a_i - b_j||, term2 = mean_j min_i ||a_i - b_j||.
// Strategy: min over squared distances (sqrt is monotone -> sqrt at the end),
// atomicMin on float-as-uint bit patterns (valid for non-negative floats).

#define NPTS   16384
#define CHUNK  1024          // inner-set tile staged in LDS
#define SPLIT  (NPTS / CHUNK) // 16 chunks -> blockIdx.y
#define BLK    256

__global__ __launch_bounds__(256) void init_min_kernel(unsigned int* p, int n) {
    int i = blockIdx.x * blockDim.x + threadIdx.x;
    if (i < n) p[i] = 0x7F7FFFFFu;  // FLT_MAX bit pattern
}

__global__ __launch_bounds__(BLK, 8)
void pair_min_kernel(const float* __restrict__ s1, const float* __restrict__ s2,
                     unsigned int* __restrict__ rowmin, unsigned int* __restrict__ colmin) {
    __shared__ float4 tile[CHUNK];

    const int dir = blockIdx.z;           // 0: A=s1,B=s2 -> rowmin ; 1: swapped -> colmin
    const float* __restrict__ A = dir ? s2 : s1;
    const float* __restrict__ B = dir ? s1 : s2;
    unsigned int* __restrict__ outmin = dir ? colmin : rowmin;

    const int i     = blockIdx.x * BLK + threadIdx.x;   // my outer point
    const int cbase = blockIdx.y * CHUNK;               // inner-set chunk base

    // Stage the inner chunk into LDS (coalesced float3 -> float4).
    #pragma unroll
    for (int k = 0; k < CHUNK / BLK; ++k) {
        int j = k * BLK + threadIdx.x;
        int g = cbase + j;
        tile[j] = make_float4(B[3 * g], B[3 * g + 1], B[3 * g + 2], 0.0f);
    }
    __syncthreads();

    const float ax = A[3 * i], ay = A[3 * i + 1], az = A[3 * i + 2];

    float m = 3.402823466e+38f;
    // All lanes read the same LDS address each iteration -> broadcast, no conflicts.
    #pragma unroll 4
    for (int j = 0; j < CHUNK; j += 2) {
        float4 b0 = tile[j];
        float4 b1 = tile[j + 1];
        float dx0 = ax - b0.x, dy0 = ay - b0.y, dz0 = az - b0.z;
        float dx1 = ax - b1.x, dy1 = ay - b1.y, dz1 = az - b1.z;
        float d0 = fmaf(dx0, dx0, fmaf(dy0, dy0, dz0 * dz0));
        float d1 = fmaf(dx1, dx1, fmaf(dy1, dy1, dz1 * dz1));
        m = fminf(m, fminf(d0, d1));   // clang can fuse to v_min3_f32
    }
    atomicMin(&outmin[i], __float_as_uint(m));
}

__global__ __launch_bounds__(1024)
void reduce_kernel(const unsigned int* __restrict__ rowmin,
                   const unsigned int* __restrict__ colmin,
                   float* __restrict__ out) {
    const int tid = threadIdx.x;
    double s = 0.0;
    for (int i = tid; i < NPTS; i += 1024) {
        s += sqrt((double)__uint_as_float(rowmin[i]));
        s += sqrt((double)__uint_as_float(colmin[i]));
    }
    // wave (64-lane) reduction
    for (int off = 32; off > 0; off >>= 1) s += __shfl_down(s, off);
    __shared__ double wsum[16];
    if ((tid & 63) == 0) wsum[tid >> 6] = s;
    __syncthreads();
    if (tid == 0) {
        double t = 0.0;
        #pragma unroll
        for (int w = 0; w < 16; ++w) t += wsum[w];
        // N == M == 16384: term1 + term2 = (sum1 + sum2) / 16384
        out[0] = (float)(t / (double)NPTS);
    }
}

extern "C" void kernel_launch(void* const* d_in, const int* in_sizes, int n_in,
                              void* d_out, int out_size, void* d_ws, size_t ws_size,
                              hipStream_t stream) {
    const float* s1 = (const float*)d_in[0];
    const float* s2 = (const float*)d_in[1];
    float* out = (float*)d_out;

    unsigned int* rowmin = (unsigned int*)d_ws;          // NPTS uints
    unsigned int* colmin = rowmin + NPTS;                // NPTS uints

    // ws is re-poisoned before every timed call -> must re-init every launch.
    init_min_kernel<<<(2 * NPTS + 255) / 256, 256, 0, stream>>>(rowmin, 2 * NPTS);

    dim3 grid(NPTS / BLK, SPLIT, 2);   // 64 x 16 x 2 = 2048 blocks
    pair_min_kernel<<<grid, BLK, 0, stream>>>(s1, s2, rowmin, colmin);

    reduce_kernel<<<1, 1024, 0, stream>>>(rowmin, colmin, out);
}

// Round 2
// 133.479 us; speedup vs baseline: 1.4664x; 1.4664x over previous
//
#include <hip/hip_runtime.h>
#include <hip/hip_bf16.h>

// Averaged Hausdorff distance between two 16384x3 fp32 point sets.
// term1 = mean_i min_j ||a_i - b_j||, term2 = mean_j min_i ||a_i - b_j||.
// Min over squared distances (sqrt monotone -> sqrt once per point at the end),
// atomicMin on float-as-uint bit patterns (valid for non-negative floats).
//
// R1 -> R2: register-tile P=8 outer points per thread. R1 was LDS-issue-bound:
// one broadcast ds_read_b128 per 64 pairs = 394K cyc/CU ~= the whole 152us.
// Now one ds_read serves 512 pairs; VALU (7 inst/pair) becomes the limit.

#define NPTS   16384
#define CHUNK  512            // inner-set tile staged in LDS
#define SPLIT  (NPTS / CHUNK) // 32 chunks -> blockIdx.y
#define BLK    256
#define P      8              // outer points per thread

__global__ __launch_bounds__(256) void init_min_kernel(unsigned int* p, int n) {
    int i = blockIdx.x * blockDim.x + threadIdx.x;
    if (i < n) p[i] = 0x7F7FFFFFu;  // FLT_MAX bit pattern
}

__global__ __launch_bounds__(BLK)
void pair_min_kernel(const float* __restrict__ s1, const float* __restrict__ s2,
                     unsigned int* __restrict__ rowmin, unsigned int* __restrict__ colmin) {
    __shared__ float4 tile[CHUNK];

    const int dir = blockIdx.z;           // 0: A=s1,B=s2 -> rowmin ; 1: swapped -> colmin
    const float* __restrict__ A = dir ? s2 : s1;
    const float* __restrict__ B = dir ? s1 : s2;
    unsigned int* __restrict__ outmin = dir ? colmin : rowmin;

    const int tid   = threadIdx.x;
    const int obase = blockIdx.x * (BLK * P);   // outer-point base for this block
    const int cbase = blockIdx.y * CHUNK;       // inner-set chunk base

    // Stage the inner chunk into LDS (float3 -> float4).
    #pragma unroll
    for (int k = 0; k < CHUNK / BLK; ++k) {
        int j = k * BLK + tid;
        int g = cbase + j;
        tile[j] = make_float4(B[3 * g], B[3 * g + 1], B[3 * g + 2], 0.0f);
    }
    __syncthreads();

    // Load my P outer points (stride-BLK for coalescing).
    float ax[P], ay[P], az[P], mn[P];
    #pragma unroll
    for (int p = 0; p < P; ++p) {
        int i = obase + p * BLK + tid;
        ax[p] = A[3 * i];
        ay[p] = A[3 * i + 1];
        az[p] = A[3 * i + 2];
        mn[p] = 3.402823466e+38f;
    }

    // One broadcast ds_read_b128 now serves P*64 pairs; 8 independent
    // FMA chains per thread give the ILP to hide VALU latency.
    for (int j = 0; j < CHUNK; j += 2) {
        float4 b0 = tile[j];
        float4 b1 = tile[j + 1];
        #pragma unroll
        for (int p = 0; p < P; ++p) {
            float dx0 = ax[p] - b0.x, dy0 = ay[p] - b0.y, dz0 = az[p] - b0.z;
            float dx1 = ax[p] - b1.x, dy1 = ay[p] - b1.y, dz1 = az[p] - b1.z;
            float d0 = fmaf(dx0, dx0, fmaf(dy0, dy0, dz0 * dz0));
            float d1 = fmaf(dx1, dx1, fmaf(dy1, dy1, dz1 * dz1));
            mn[p] = fminf(mn[p], fminf(d0, d1));   // -> v_min3_f32
        }
    }

    #pragma unroll
    for (int p = 0; p < P; ++p) {
        atomicMin(&outmin[obase + p * BLK + tid], __float_as_uint(mn[p]));
    }
}

__global__ __launch_bounds__(1024)
void reduce_kernel(const unsigned int* __restrict__ rowmin,
                   const unsigned int* __restrict__ colmin,
                   float* __restrict__ out) {
    const int tid = threadIdx.x;
    double s = 0.0;
    for (int i = tid; i < NPTS; i += 1024) {
        s += (double)sqrtf(__uint_as_float(rowmin[i]));
        s += (double)sqrtf(__uint_as_float(colmin[i]));
    }
    // wave (64-lane) reduction
    for (int off = 32; off > 0; off >>= 1) s += __shfl_down(s, off);
    __shared__ double wsum[16];
    if ((tid & 63) == 0) wsum[tid >> 6] = s;
    __syncthreads();
    if (tid == 0) {
        double t = 0.0;
        #pragma unroll
        for (int w = 0; w < 16; ++w) t += wsum[w];
        // N == M == 16384: term1 + term2 = (sum1 + sum2) / 16384
        out[0] = (float)(t / (double)NPTS);
    }
}

extern "C" void kernel_launch(void* const* d_in, const int* in_sizes, int n_in,
                              void* d_out, int out_size, void* d_ws, size_t ws_size,
                              hipStream_t stream) {
    const float* s1 = (const float*)d_in[0];
    const float* s2 = (const float*)d_in[1];
    float* out = (float*)d_out;

    unsigned int* rowmin = (unsigned int*)d_ws;          // NPTS uints
    unsigned int* colmin = rowmin + NPTS;                // NPTS uints

    // ws is re-poisoned before every timed call -> must re-init every launch.
    init_min_kernel<<<(2 * NPTS + 255) / 256, 256, 0, stream>>>(rowmin, 2 * NPTS);

    dim3 grid(NPTS / (BLK * P), SPLIT, 2);   // 8 x 32 x 2 = 512 blocks
    pair_min_kernel<<<grid, BLK, 0, stream>>>(s1, s2, rowmin, colmin);

    reduce_kernel<<<1, 1024, 0, stream>>>(rowmin, colmin, out);
}

// Round 3
// 110.406 us; speedup vs baseline: 1.7729x; 1.2090x over previous
//
#include <hip/hip_runtime.h>
#include <hip/hip_bf16.h>

// Averaged Hausdorff distance between two 16384x3 fp32 point sets.
// term1 = mean_i min_j ||a_i - b_j||, term2 = mean_j min_i ||a_i - b_j||.
//
// R2 -> R3:
//  (a) expanded form: d^2/2 = (|a|^2+|b|^2)/2 - a.b  -> 4 VALU ops/pair
//      (1 add + 3 fma-with-negate) vs 7 for direct form. Sets pre-packed as
//      float4(x,y,z, 0.5*|p|^2) by a pack kernel.
//  (b) occupancy 2 -> 4 blocks/CU (CHUNK=256, grid 1024) to cover LDS/loop
//      latency; R2 ran at ~55% real VALU busy (derived counter ~2x overcounts
//      on gfx950: SIMD-32 issues wave64 in 2 cyc, formula assumes 4).
//  (c) parallel reduce (64 blocks, double atomicAdd) + finalize kernel.
// Min over d^2/2 via atomicMin on float bit patterns (valid: clamped >= 0).

#define NPTS   16384
#define BLK    256
#define P      8               // outer points per thread
#define CHUNK  256             // inner-set tile staged in LDS (== BLK)
#define SPLIT  (NPTS / CHUNK)  // 64 -> blockIdx.y

__global__ __launch_bounds__(256)
void pack_init_kernel(const float* __restrict__ s1, const float* __restrict__ s2,
                      float4* __restrict__ pk1, float4* __restrict__ pk2,
                      unsigned int* __restrict__ rowmin, unsigned int* __restrict__ colmin,
                      double* __restrict__ accum) {
    int i = blockIdx.x * blockDim.x + threadIdx.x;
    if (i < NPTS) {
        float x1 = s1[3 * i], y1 = s1[3 * i + 1], z1 = s1[3 * i + 2];
        pk1[i] = make_float4(x1, y1, z1, 0.5f * (x1 * x1 + y1 * y1 + z1 * z1));
        float x2 = s2[3 * i], y2 = s2[3 * i + 1], z2 = s2[3 * i + 2];
        pk2[i] = make_float4(x2, y2, z2, 0.5f * (x2 * x2 + y2 * y2 + z2 * z2));
        rowmin[i] = 0x7F7FFFFFu;   // FLT_MAX bit pattern
        colmin[i] = 0x7F7FFFFFu;
    }
    if (i == 0) accum[0] = 0.0;
}

__global__ __launch_bounds__(BLK, 4)
void pair_min_kernel(const float4* __restrict__ pk1, const float4* __restrict__ pk2,
                     unsigned int* __restrict__ rowmin, unsigned int* __restrict__ colmin) {
    __shared__ float4 tile[CHUNK];

    const int dir = blockIdx.z;           // 0: A=pk1,B=pk2 -> rowmin ; 1: swapped
    const float4* __restrict__ A = dir ? pk2 : pk1;
    const float4* __restrict__ B = dir ? pk1 : pk2;
    unsigned int* __restrict__ outmin = dir ? colmin : rowmin;

    const int tid   = threadIdx.x;
    const int obase = blockIdx.x * (BLK * P);   // outer-point base
    const int cbase = blockIdx.y * CHUNK;       // inner chunk base

    tile[tid] = B[cbase + tid];                 // CHUNK == BLK: one float4 each
    __syncthreads();

    float ax[P], ay[P], az[P], sa[P], mn[P];
    #pragma unroll
    for (int p = 0; p < P; ++p) {
        float4 a = A[obase + p * BLK + tid];
        ax[p] = a.x; ay[p] = a.y; az[p] = a.z; sa[p] = a.w;
        mn[p] = 3.402823466e+38f;
    }

    // Per pair: t = (sa+sb) - ax*bx - ay*by - az*bz  = d^2/2
    // 1 v_add + 3 v_fma (negate modifier is free) + amortized min tree.
    for (int j = 0; j < CHUNK; j += 4) {
        float4 b0 = tile[j], b1 = tile[j + 1], b2 = tile[j + 2], b3 = tile[j + 3];
        #pragma unroll
        for (int p = 0; p < P; ++p) {
            float t0 = sa[p] + b0.w;
            t0 = fmaf(-ax[p], b0.x, t0); t0 = fmaf(-ay[p], b0.y, t0); t0 = fmaf(-az[p], b0.z, t0);
            float t1 = sa[p] + b1.w;
            t1 = fmaf(-ax[p], b1.x, t1); t1 = fmaf(-ay[p], b1.y, t1); t1 = fmaf(-az[p], b1.z, t1);
            float t2 = sa[p] + b2.w;
            t2 = fmaf(-ax[p], b2.x, t2); t2 = fmaf(-ay[p], b2.y, t2); t2 = fmaf(-az[p], b2.z, t2);
            float t3 = sa[p] + b3.w;
            t3 = fmaf(-ax[p], b3.x, t3); t3 = fmaf(-ay[p], b3.y, t3); t3 = fmaf(-az[p], b3.z, t3);
            mn[p] = fminf(mn[p], fminf(fminf(t0, t1), fminf(t2, t3)));  // min3 fusable
        }
    }

    #pragma unroll
    for (int p = 0; p < P; ++p) {
        // clamp: cancellation could (theoretically) give tiny negative d^2/2,
        // which would break the uint bit-order min trick.
        atomicMin(&outmin[obase + p * BLK + tid], __float_as_uint(fmaxf(mn[p], 0.0f)));
    }
}

__global__ __launch_bounds__(256)
void reduce_kernel(const unsigned int* __restrict__ rowmin,
                   const unsigned int* __restrict__ colmin,
                   double* __restrict__ accum) {
    const int tid = threadIdx.x;
    const int i = blockIdx.x * 256 + tid;     // grid 64 blocks -> 16384 threads
    // stored value is d^2/2 -> d = sqrt(2*t)
    double s = (double)sqrtf(2.0f * __uint_as_float(rowmin[i]))
             + (double)sqrtf(2.0f * __uint_as_float(colmin[i]));
    for (int off = 32; off > 0; off >>= 1) s += __shfl_down(s, off);
    __shared__ double w[4];
    if ((tid & 63) == 0) w[tid >> 6] = s;
    __syncthreads();
    if (tid == 0) atomicAdd(accum, w[0] + w[1] + w[2] + w[3]);
}

__global__ void finalize_kernel(const double* __restrict__ accum, float* __restrict__ out) {
    // N == M == 16384: term1 + term2 = (sum1 + sum2) / 16384
    out[0] = (float)(accum[0] / (double)NPTS);
}

extern "C" void kernel_launch(void* const* d_in, const int* in_sizes, int n_in,
                              void* d_out, int out_size, void* d_ws, size_t ws_size,
                              hipStream_t stream) {
    const float* s1 = (const float*)d_in[0];
    const float* s2 = (const float*)d_in[1];
    float* out = (float*)d_out;

    // ws layout
    float4* pk1 = (float4*)d_ws;                          // 16384 * 16B
    float4* pk2 = pk1 + NPTS;                             // 16384 * 16B
    unsigned int* rowmin = (unsigned int*)(pk2 + NPTS);   // 16384 * 4B
    unsigned int* colmin = rowmin + NPTS;                 // 16384 * 4B
    double* accum = (double*)(colmin + NPTS);             // 8B

    // ws re-poisoned before every timed call -> re-init every launch.
    pack_init_kernel<<<NPTS / 256, 256, 0, stream>>>(s1, s2, pk1, pk2, rowmin, colmin, accum);

    dim3 grid(NPTS / (BLK * P), SPLIT, 2);   // 8 x 64 x 2 = 1024 blocks
    pair_min_kernel<<<grid, BLK, 0, stream>>>(pk1, pk2, rowmin, colmin);

    reduce_kernel<<<NPTS / 256, 256, 0, stream>>>(rowmin, colmin, accum);
    finalize_kernel<<<1, 1, 0, stream>>>(accum, out);
}